// Round 1
// baseline (516.619 us; speedup 1.0000x reference)
//
#include <hip/hip_runtime.h>
#include <hip/hip_bf16.h>
#include <stdint.h>

#define SEQ    4096
#define DMODEL 1024
#define NHEAD  16
#define HDIM   64
#define NBATCH 4
#define NBH    (NBATCH*NHEAD)     // 64
#define MTOK   (NBATCH*SEQ)       // 16384
#define FEPS   1e-6f

typedef float f32x4 __attribute__((ext_vector_type(4)));
typedef short bf16x8 __attribute__((ext_vector_type(8)));

// ---------- workspace layout (bytes) ----------
#define XB_OFF    0u                      // 16384*1024 bf16 = 33554432
#define WQKV_OFF  33554432u               // 3072*1024 bf16  = 6291456
#define WO_OFF    39845888u               // 1024*1024 bf16  = 2097152
#define QKV_OFF   41943040u               // 16384*3072 bf16 = 100663296
#define AOB_OFF   142606336u              // 16384*1024 bf16 = 33554432
#define ST_OFF    176160768u
#define KSUM_OFF  (ST_OFF)                // 4096 f32
#define QSUM_OFF  (ST_OFF + 16384u)
#define QSI_OFF   (ST_OFF + 32768u)
#define KSO_OFF   (ST_OFF + 49152u)
#define ESUM_OFF  (ST_OFF + 65536u)       // 64 f32 (padded)
#define SI_OFF    (ST_OFF + 81920u)       // 262144 f32 = 1 MB
#define SA_OFF    (SI_OFF + 1048576u)
#define EE_OFF    (SA_OFF + 1048576u)
#define KVF_OFF   (EE_OFF + 1048576u)     // 64*64*64 f32 = 1 MB
#define KVP_OFF   (KVF_OFF + 1048576u)    // 8 MB partials

__device__ __forceinline__ unsigned short f2bf(float f) {
  __hip_bfloat16 h = __float2bfloat16(f);
  unsigned short u; __builtin_memcpy(&u, &h, 2); return u;
}
__device__ __forceinline__ float bf2f(unsigned short u) {
  union { unsigned u; float f; } x; x.u = ((unsigned)u) << 16; return x.f;
}
__device__ __forceinline__ void decode8(uint4 r, float* o) {
  o[0] = bf2f((unsigned short)(r.x & 0xffffu)); o[1] = bf2f((unsigned short)(r.x >> 16));
  o[2] = bf2f((unsigned short)(r.y & 0xffffu)); o[3] = bf2f((unsigned short)(r.y >> 16));
  o[4] = bf2f((unsigned short)(r.z & 0xffffu)); o[5] = bf2f((unsigned short)(r.z >> 16));
  o[6] = bf2f((unsigned short)(r.w & 0xffffu)); o[7] = bf2f((unsigned short)(r.w >> 16));
}

// ---------- conversions ----------
__global__ __launch_bounds__(256) void conv_x_k(const float* __restrict__ x,
                                                unsigned short* __restrict__ xb, int n) {
  int i = (blockIdx.x * 256 + threadIdx.x) * 4;
  const int stride = gridDim.x * 256 * 4;
  for (; i < n; i += stride) {
    float4 v = *(const float4*)(x + i);
    ushort4 o;
    o.x = f2bf(v.x); o.y = f2bf(v.y); o.z = f2bf(v.z); o.w = f2bf(v.w);
    *(ushort4*)(xb + i) = o;
  }
}

// transpose+convert W (K x N) -> Wt (N x K) bf16
__global__ __launch_bounds__(256) void convw_k(const float* __restrict__ Wq, const float* __restrict__ Wk,
                                               const float* __restrict__ Wv, const float* __restrict__ Wo,
                                               unsigned short* __restrict__ Wqkvt,
                                               unsigned short* __restrict__ Wot) {
  __shared__ float tile[64][65];
  const int z = blockIdx.z;
  const float* W = (z == 0) ? Wq : (z == 1) ? Wk : (z == 2) ? Wv : Wo;
  unsigned short* dst = (z < 3) ? (Wqkvt + (size_t)z * 1024u * 1024u) : Wot;
  const int n0 = blockIdx.x * 64, k0 = blockIdx.y * 64;
  const int tx = threadIdx.x & 63, ty = threadIdx.x >> 6;
  for (int i = ty; i < 64; i += 4)
    tile[i][tx] = W[(size_t)(k0 + i) * 1024 + n0 + tx];
  __syncthreads();
  for (int i = ty; i < 64; i += 4)
    dst[(size_t)(n0 + i) * 1024 + k0 + tx] = f2bf(tile[tx][i]);
}

// ---------- GEMM: C(M,N) = A(M,K) @ Bt(N,K)^T, 128x128 tile, BK=32 ----------
// MODE 0: N=3072, bias b0/b1/b2 per 1024-col group, sigmoid on cols<2048, bf16 out
// MODE 1: N=1024, bias b0, fp32 out
template <int MODE>
__global__ __launch_bounds__(256) void gemm_bt(const unsigned short* __restrict__ A,
                                               const unsigned short* __restrict__ Bt,
                                               const float* __restrict__ b0,
                                               const float* __restrict__ b1,
                                               const float* __restrict__ b2,
                                               void* __restrict__ C, int Ndim, int Kdim) {
  __shared__ unsigned short As[128 * 32];
  __shared__ unsigned short Bs[128 * 32];
  const int t = threadIdx.x;
  const int n0 = blockIdx.x * 128, m0 = blockIdx.y * 128;
  const int lane = t & 63;
  const int wr = ((t >> 6) >> 1) * 64, wc = ((t >> 6) & 1) * 64;
  const int r = lane & 15, ko = (lane >> 4) * 8;

  f32x4 acc[4][4];
#pragma unroll
  for (int i = 0; i < 4; ++i)
#pragma unroll
    for (int j = 0; j < 4; ++j) acc[i][j] = (f32x4){0.f, 0.f, 0.f, 0.f};

  for (int k0 = 0; k0 < Kdim; k0 += 32) {
#pragma unroll
    for (int j = 0; j < 2; ++j) {
      const int f = j * 256 + t;
      const unsigned short* ga = A + (size_t)(m0 + (f >> 2)) * Kdim + k0 + (f & 3) * 8;
      __builtin_amdgcn_global_load_lds((const __attribute__((address_space(1))) void*)ga,
                                       (__attribute__((address_space(3))) void*)(As + f * 8), 16, 0, 0);
    }
#pragma unroll
    for (int j = 0; j < 2; ++j) {
      const int f = j * 256 + t;
      const unsigned short* gb = Bt + (size_t)(n0 + (f >> 2)) * Kdim + k0 + (f & 3) * 8;
      __builtin_amdgcn_global_load_lds((const __attribute__((address_space(1))) void*)gb,
                                       (__attribute__((address_space(3))) void*)(Bs + f * 8), 16, 0, 0);
    }
    __syncthreads();
    bf16x8 av[4], bv[4];
#pragma unroll
    for (int i = 0; i < 4; ++i) av[i] = *(const bf16x8*)(As + (wr + i * 16 + r) * 32 + ko);
#pragma unroll
    for (int j = 0; j < 4; ++j) bv[j] = *(const bf16x8*)(Bs + (wc + j * 16 + r) * 32 + ko);
#pragma unroll
    for (int i = 0; i < 4; ++i)
#pragma unroll
      for (int j = 0; j < 4; ++j)
        acc[i][j] = __builtin_amdgcn_mfma_f32_16x16x32_bf16(av[i], bv[j], acc[i][j], 0, 0, 0);
    __syncthreads();
  }

  const int cr = (lane >> 4) * 4, cc = lane & 15;
#pragma unroll
  for (int i = 0; i < 4; ++i)
#pragma unroll
    for (int j = 0; j < 4; ++j)
#pragma unroll
      for (int rr = 0; rr < 4; ++rr) {
        const int gr = m0 + wr + i * 16 + cr + rr;
        const int gc = n0 + wc + j * 16 + cc;
        float v = acc[i][j][rr];
        if (MODE == 0) {
          const float bias = (gc < 1024) ? b0[gc] : ((gc < 2048) ? b1[gc - 1024] : b2[gc - 2048]);
          v += bias;
          if (gc < 2048) v = 1.f / (1.f + __expf(-v));
          ((unsigned short*)C)[(size_t)gr * Ndim + gc] = f2bf(v);
        } else {
          v += b0[gc];
          ((float*)C)[(size_t)gr * Ndim + gc] = v;
        }
      }
}

// ---------- flow statistics ----------
// grid NBH*8; block 256. ksum/qsum accumulation.
__global__ __launch_bounds__(256) void sums_k(const unsigned short* __restrict__ QKV,
                                              float* __restrict__ ksum, float* __restrict__ qsum) {
  const int bh = blockIdx.x >> 3, c = blockIdx.x & 7;
  const int b = bh >> 4, h = bh & 15;
  const int d = threadIdx.x & 63, part = threadIdx.x >> 6;
  const size_t base = (size_t)b * SEQ * 3072 + h * 64 + d;
  float qa = 0.f, ka = 0.f;
  for (int l = c * 512 + part; l < (c + 1) * 512; l += 4) {
    const size_t off = base + (size_t)l * 3072;
    qa += bf2f(QKV[off]);
    ka += bf2f(QKV[off + 1024]);
  }
  __shared__ float red[2][4][64];
  red[0][part][d] = qa; red[1][part][d] = ka;
  __syncthreads();
  if (part == 0) {
    qa = red[0][0][d] + red[0][1][d] + red[0][2][d] + red[0][3][d];
    ka = red[1][0][d] + red[1][1][d] + red[1][2][d] + red[1][3][d];
    atomicAdd(&qsum[bh * 64 + d], qa);
    atomicAdd(&ksum[bh * 64 + d], ka);
  }
}

// si, qsi_sum, kso_sum
__global__ __launch_bounds__(256) void flow1_k(const unsigned short* __restrict__ QKV,
                                               const float* __restrict__ ksum, const float* __restrict__ qsum,
                                               float* __restrict__ si, float* __restrict__ qsi,
                                               float* __restrict__ kso) {
  const int bh = blockIdx.x >> 3, c = blockIdx.x & 7;
  const int b = bh >> 4, h = bh & 15;
  const int w = threadIdx.x >> 6, lane = threadIdx.x & 63;
  const float ks = ksum[bh * 64 + lane] + FEPS;
  const float qs = qsum[bh * 64 + lane] + FEPS;
  const size_t base = (size_t)b * SEQ * 3072 + h * 64 + lane;
  float qsi_acc = 0.f, kso_acc = 0.f;
  const int l0 = c * 512 + w * 128;
  for (int l = l0; l < l0 + 128; ++l) {
    const size_t off = base + (size_t)l * 3072;
    const float qv = bf2f(QKV[off]);
    const float kv = bf2f(QKV[off + 1024]);
    float dq = (qv + FEPS) * ks;
    float dk = (kv + FEPS) * qs;
#pragma unroll
    for (int m = 1; m < 64; m <<= 1) { dq += __shfl_xor(dq, m); dk += __shfl_xor(dk, m); }
    const float siv = 1.f / dq, sov = 1.f / dk;
    if (lane == 0) si[(size_t)bh * SEQ + l] = siv;
    qsi_acc += qv * siv;
    kso_acc += kv * sov;
  }
  atomicAdd(&qsi[bh * 64 + lane], qsi_acc);
  atomicAdd(&kso[bh * 64 + lane], kso_acc);
}

// sink_allocation, ee = exp(clip(conserved_source)), esum
__global__ __launch_bounds__(256) void flow2_k(const unsigned short* __restrict__ QKV,
                                               const float* __restrict__ qsi, const float* __restrict__ kso,
                                               float* __restrict__ sa, float* __restrict__ ee,
                                               float* __restrict__ esum) {
  const int bh = blockIdx.x >> 3, c = blockIdx.x & 7;
  const int b = bh >> 4, h = bh & 15;
  const int w = threadIdx.x >> 6, lane = threadIdx.x & 63;
  const float kov = kso[bh * 64 + lane] + FEPS;
  const float qiv = qsi[bh * 64 + lane] + FEPS;
  const size_t base = (size_t)b * SEQ * 3072 + h * 64 + lane;
  float es = 0.f;
  const int l0 = c * 512 + w * 128;
  for (int l = l0; l < l0 + 128; ++l) {
    const size_t off = base + (size_t)l * 3072;
    const float qv = bf2f(QKV[off]);
    const float kv = bf2f(QKV[off + 1024]);
    float ds = (qv + FEPS) * kov;
    float dr = (kv + FEPS) * qiv;
#pragma unroll
    for (int m = 1; m < 64; m <<= 1) { ds += __shfl_xor(ds, m); dr += __shfl_xor(dr, m); }
    const float sig = 1.f / (1.f + __expf(-ds));
    const float cs = fminf(1.f, fmaxf(-1.f, dr));
    const float e = __expf(cs);
    if (lane == 0) { sa[(size_t)bh * SEQ + l] = sig; ee[(size_t)bh * SEQ + l] = e; }
    es += e;
  }
  if (lane == 0) atomicAdd(&esum[bh], es);
}

// kv partials: grid NBH*8, each block covers 512 rows
__global__ __launch_bounds__(256) void kvpart_k(const unsigned short* __restrict__ QKV,
                                                const float* __restrict__ ee, const float* __restrict__ esum,
                                                float* __restrict__ kvp) {
  const int bh = blockIdx.x >> 3, c = blockIdx.x & 7;
  const int b = bh >> 4, h = bh & 15;
  const float Ls = 4096.f / esum[bh];
  __shared__ float kch[32][64];
  __shared__ float vch[32][64];
  const int t = threadIdx.x;
  const int sl = t >> 3, sd = (t & 7) * 8;
  const int d1 = (t >> 4) * 4, d2 = (t & 15) * 4;
  const size_t rowbase = (size_t)b * SEQ * 3072 + h * 64;
  float acc[4][4] = {};
  for (int ch = 0; ch < 16; ++ch) {
    const int l0 = c * 512 + ch * 32;
    const size_t off = rowbase + (size_t)(l0 + sl) * 3072 + sd;
    const uint4 kr = *(const uint4*)(QKV + off + 1024);
    const uint4 vr = *(const uint4*)(QKV + off + 2048);
    const float cmp = ee[(size_t)bh * SEQ + l0 + sl] * Ls;
    float kd[8], vd[8];
    decode8(kr, kd); decode8(vr, vd);
    __syncthreads();
    *(f32x4*)&kch[sl][sd]     = (f32x4){kd[0], kd[1], kd[2], kd[3]};
    *(f32x4*)&kch[sl][sd + 4] = (f32x4){kd[4], kd[5], kd[6], kd[7]};
    *(f32x4*)&vch[sl][sd]     = (f32x4){vd[0] * cmp, vd[1] * cmp, vd[2] * cmp, vd[3] * cmp};
    *(f32x4*)&vch[sl][sd + 4] = (f32x4){vd[4] * cmp, vd[5] * cmp, vd[6] * cmp, vd[7] * cmp};
    __syncthreads();
    for (int l = 0; l < 32; ++l) {
      const f32x4 ka = *(const f32x4*)&kch[l][d1];
      const f32x4 vb = *(const f32x4*)&vch[l][d2];
#pragma unroll
      for (int i = 0; i < 4; ++i)
#pragma unroll
        for (int j = 0; j < 4; ++j) acc[i][j] += ka[i] * vb[j];
    }
    __syncthreads();
  }
  float* dst = kvp + (size_t)blockIdx.x * 4096;
#pragma unroll
  for (int i = 0; i < 4; ++i)
    *(f32x4*)&dst[(d1 + i) * 64 + d2] = (f32x4){acc[i][0], acc[i][1], acc[i][2], acc[i][3]};
}

__global__ __launch_bounds__(256) void kvred_k(const float* __restrict__ kvp, float* __restrict__ kvf) {
  const int idx = blockIdx.x * 256 + threadIdx.x;
  const int bh = idx >> 12, e = idx & 4095;
  float s = 0.f;
#pragma unroll
  for (int cN = 0; cN < 8; ++cN) s += kvp[((size_t)(bh * 8 + cN) << 12) + e];
  kvf[idx] = s;
}

// out = (q*si)@kv * sa  -> bf16 AOb in (B,L,D) head-merged layout. grid NBH*16.
__global__ __launch_bounds__(256) void outk_k(const unsigned short* __restrict__ QKV,
                                              const float* __restrict__ kvf, const float* __restrict__ si,
                                              const float* __restrict__ sa,
                                              unsigned short* __restrict__ AOb) {
  const int bh = blockIdx.x >> 4, lc = blockIdx.x & 15;
  const int b = bh >> 4, h = bh & 15;
  __shared__ float kvs[4096];
  __shared__ float qs_[64 * 128];
  const int t = threadIdx.x;
  for (int i = t; i < 1024; i += 256)
    *(f32x4*)&kvs[i * 4] = *(const f32x4*)&kvf[(size_t)bh * 4096 + i * 4];
  const size_t rowbase = (size_t)b * SEQ * 3072 + h * 64;
  const int lb = (t >> 4) * 8, d2 = (t & 15) * 4;
  const int sl = t & 127, sd0 = (t >> 7) * 8;
  for (int sub = 0; sub < 2; ++sub) {
    const int l0 = lc * 256 + sub * 128;
    __syncthreads();
#pragma unroll
    for (int p = 0; p < 4; ++p) {
      const int d0 = sd0 + p * 16;
      const uint4 raw = *(const uint4*)(QKV + rowbase + (size_t)(l0 + sl) * 3072 + d0);
      float qd[8]; decode8(raw, qd);
#pragma unroll
      for (int i = 0; i < 8; ++i) qs_[(d0 + i) * 128 + sl] = qd[i];
    }
    __syncthreads();
    float acc[8][4] = {};
    for (int dd = 0; dd < 64; ++dd) {
      const f32x4 kvv = *(const f32x4*)&kvs[dd * 64 + d2];
      const f32x4 qa = *(const f32x4*)&qs_[dd * 128 + lb];
      const f32x4 qb = *(const f32x4*)&qs_[dd * 128 + lb + 4];
#pragma unroll
      for (int i = 0; i < 4; ++i)
#pragma unroll
        for (int j = 0; j < 4; ++j) { acc[i][j] += qa[i] * kvv[j]; acc[i + 4][j] += qb[i] * kvv[j]; }
    }
#pragma unroll
    for (int i = 0; i < 8; ++i) {
      const int l = l0 + lb + i;
      const size_t sidx = (size_t)bh * SEQ + l;
      const float sc = si[sidx] * sa[sidx];
      ushort4 o;
      o.x = f2bf(acc[i][0] * sc); o.y = f2bf(acc[i][1] * sc);
      o.z = f2bf(acc[i][2] * sc); o.w = f2bf(acc[i][3] * sc);
      *(ushort4*)(AOb + (size_t)(b * SEQ + l) * 1024 + h * 64 + d2) = o;
    }
  }
}

extern "C" void kernel_launch(void* const* d_in, const int* in_sizes, int n_in,
                              void* d_out, int out_size, void* d_ws, size_t ws_size,
                              hipStream_t stream) {
  const float* x  = (const float*)d_in[0];
  const float* Wq = (const float*)d_in[1];
  const float* bq = (const float*)d_in[2];
  const float* Wk = (const float*)d_in[3];
  const float* bk = (const float*)d_in[4];
  const float* Wv = (const float*)d_in[5];
  const float* bv = (const float*)d_in[6];
  const float* Wo = (const float*)d_in[7];
  const float* bo = (const float*)d_in[8];
  char* ws = (char*)d_ws;
  unsigned short* Xb    = (unsigned short*)(ws + XB_OFF);
  unsigned short* Wqkvt = (unsigned short*)(ws + WQKV_OFF);
  unsigned short* Wot   = (unsigned short*)(ws + WO_OFF);
  unsigned short* QKV   = (unsigned short*)(ws + QKV_OFF);
  unsigned short* AOb   = (unsigned short*)(ws + AOB_OFF);
  float* ksum = (float*)(ws + KSUM_OFF);
  float* qsum = (float*)(ws + QSUM_OFF);
  float* qsi  = (float*)(ws + QSI_OFF);
  float* kso  = (float*)(ws + KSO_OFF);
  float* esum = (float*)(ws + ESUM_OFF);
  float* si   = (float*)(ws + SI_OFF);
  float* sa   = (float*)(ws + SA_OFF);
  float* ee   = (float*)(ws + EE_OFF);
  float* kvf  = (float*)(ws + KVF_OFF);
  float* kvp  = (float*)(ws + KVP_OFF);

  (void)hipMemsetAsync(ws + ST_OFF, 0, 81920, stream);  // zero atomic accumulators
  conv_x_k<<<2048, 256, 0, stream>>>(x, Xb, MTOK * DMODEL);
  convw_k<<<dim3(16, 16, 4), 256, 0, stream>>>(Wq, Wk, Wv, Wo, Wqkvt, Wot);
  gemm_bt<0><<<dim3(24, 128), 256, 0, stream>>>(Xb, Wqkvt, bq, bk, bv, (void*)QKV, 3072, 1024);
  sums_k<<<NBH * 8, 256, 0, stream>>>(QKV, ksum, qsum);
  flow1_k<<<NBH * 8, 256, 0, stream>>>(QKV, ksum, qsum, si, qsi, kso);
  flow2_k<<<NBH * 8, 256, 0, stream>>>(QKV, qsi, kso, sa, ee, esum);
  kvpart_k<<<NBH * 8, 256, 0, stream>>>(QKV, ee, esum, kvp);
  kvred_k<<<1024, 256, 0, stream>>>(kvp, kvf);
  outk_k<<<NBH * 16, 256, 0, stream>>>(QKV, kvf, si, sa, AOb);
  gemm_bt<1><<<dim3(8, 128), 256, 0, stream>>>(AOb, Wot, bo, nullptr, nullptr, d_out, 1024, 1024);
}

// Round 2
// 464.987 us; speedup vs baseline: 1.1110x; 1.1110x over previous
//
#include <hip/hip_runtime.h>
#include <hip/hip_bf16.h>
#include <stdint.h>

#define SEQ    4096
#define DMODEL 1024
#define NHEAD  16
#define HDIM   64
#define NBATCH 4
#define NBH    (NBATCH*NHEAD)     // 64
#define MTOK   (NBATCH*SEQ)       // 16384
#define FEPS   1e-6f

typedef float f32x4 __attribute__((ext_vector_type(4)));
typedef short bf16x8 __attribute__((ext_vector_type(8)));

// ---------- workspace layout (bytes) ----------
#define XB_OFF    0u                      // 16384*1024 bf16 = 33554432
#define WQKV_OFF  33554432u               // 3072*1024 bf16  = 6291456
#define WO_OFF    39845888u               // 1024*1024 bf16  = 2097152
#define QKV_OFF   41943040u               // 16384*3072 bf16 = 100663296
#define AOB_OFF   142606336u              // 16384*1024 bf16 = 33554432
#define ST_OFF    176160768u
#define KSUM_OFF  (ST_OFF)                // 4096 f32
#define QSUM_OFF  (ST_OFF + 16384u)
#define QSI_OFF   (ST_OFF + 32768u)
#define KSO_OFF   (ST_OFF + 49152u)
#define ESUM_OFF  (ST_OFF + 65536u)       // 64 f32 (padded)
#define SI_OFF    (ST_OFF + 81920u)       // 262144 f32 = 1 MB
#define SA_OFF    (SI_OFF + 1048576u)
#define EE_OFF    (SA_OFF + 1048576u)
#define KVF_OFF   (EE_OFF + 1048576u)     // 64*64*64 f32 = 1 MB
#define KVP_OFF   (KVF_OFF + 1048576u)    // 8 MB partials

#define S_VMCNT(N) asm volatile("s_waitcnt vmcnt(" #N ")" ::: "memory")
#define BARRIER() do { __builtin_amdgcn_s_barrier(); asm volatile("" ::: "memory"); } while (0)

__device__ __forceinline__ unsigned short f2bf(float f) {
  __hip_bfloat16 h = __float2bfloat16(f);
  unsigned short u; __builtin_memcpy(&u, &h, 2); return u;
}
__device__ __forceinline__ float bf2f(unsigned short u) {
  union { unsigned u; float f; } x; x.u = ((unsigned)u) << 16; return x.f;
}
__device__ __forceinline__ void decode8(uint4 r, float* o) {
  o[0] = bf2f((unsigned short)(r.x & 0xffffu)); o[1] = bf2f((unsigned short)(r.x >> 16));
  o[2] = bf2f((unsigned short)(r.y & 0xffffu)); o[3] = bf2f((unsigned short)(r.y >> 16));
  o[4] = bf2f((unsigned short)(r.z & 0xffffu)); o[5] = bf2f((unsigned short)(r.z >> 16));
  o[6] = bf2f((unsigned short)(r.w & 0xffffu)); o[7] = bf2f((unsigned short)(r.w >> 16));
}

// ---------- conversions ----------
__global__ __launch_bounds__(256) void conv_x_k(const float* __restrict__ x,
                                                unsigned short* __restrict__ xb, int n) {
  int i = (blockIdx.x * 256 + threadIdx.x) * 4;
  const int stride = gridDim.x * 256 * 4;
  for (; i < n; i += stride) {
    float4 v = *(const float4*)(x + i);
    ushort4 o;
    o.x = f2bf(v.x); o.y = f2bf(v.y); o.z = f2bf(v.z); o.w = f2bf(v.w);
    *(ushort4*)(xb + i) = o;
  }
}

// transpose+convert W (K x N) -> Wt (N x K) bf16
__global__ __launch_bounds__(256) void convw_k(const float* __restrict__ Wq, const float* __restrict__ Wk,
                                               const float* __restrict__ Wv, const float* __restrict__ Wo,
                                               unsigned short* __restrict__ Wqkvt,
                                               unsigned short* __restrict__ Wot) {
  __shared__ float tile[64][65];
  const int z = blockIdx.z;
  const float* W = (z == 0) ? Wq : (z == 1) ? Wk : (z == 2) ? Wv : Wo;
  unsigned short* dst = (z < 3) ? (Wqkvt + (size_t)z * 1024u * 1024u) : Wot;
  const int n0 = blockIdx.x * 64, k0 = blockIdx.y * 64;
  const int tx = threadIdx.x & 63, ty = threadIdx.x >> 6;
  for (int i = ty; i < 64; i += 4)
    tile[i][tx] = W[(size_t)(k0 + i) * 1024 + n0 + tx];
  __syncthreads();
  for (int i = ty; i < 64; i += 4)
    dst[(size_t)(n0 + i) * 1024 + k0 + tx] = f2bf(tile[tx][i]);
}

// ---------- 8-phase 256x256 GEMM: C(M,N) = A(M,K) @ Bt(N,K)^T ----------
// BM=BN=256, BK=64, 512 threads = 8 waves (2M x 4N), per-wave out 128x64.
// LDS 128KB: [buf(2)][A0,A1,B0,B1][128][64] bf16, XOR-swizzle byte^=((row&7)<<4).
// MODE 0: N=3072, bias b0/b1/b2 per 1024-col group, sigmoid on cols<2048, bf16 out
// MODE 1: N=1024, bias b0, fp32 out

__device__ __forceinline__ void stage_half(const unsigned short* __restrict__ gsrc, int ldk,
                                           unsigned short* lds_base, int tid) {
#pragma unroll
  for (int j = 0; j < 2; ++j) {
    const int o = (tid + j * 512) * 16;                 // dest byte offset in 16KB half-tile
    const int row = o >> 7;
    const int colb = (o & 127) ^ ((row & 7) << 4);      // inverse-swizzled source column
    const unsigned short* g = gsrc + (size_t)row * ldk + (colb >> 1);
    __builtin_amdgcn_global_load_lds((const __attribute__((address_space(1))) void*)g,
        (__attribute__((address_space(3))) void*)(lds_base + (o >> 1)), 16, 0, 0);
  }
}

__device__ __forceinline__ bf16x8 ldsf(const unsigned short* base, int r, int cb) {
  const int cbs = cb ^ ((r & 7) << 4);                  // swizzled read
  return *(const bf16x8*)(base + r * 64 + (cbs >> 1));
}

template <int MODE>
__global__ __launch_bounds__(512, 2) void gemm8p(const unsigned short* __restrict__ A,
                                                 const unsigned short* __restrict__ Bt,
                                                 const float* __restrict__ b0,
                                                 const float* __restrict__ b1,
                                                 const float* __restrict__ b2,
                                                 void* __restrict__ C, int Ndim, int Kdim) {
  __shared__ unsigned short sm[8 * 8192];               // 128 KiB
  const int tid = threadIdx.x;
  const int wid = tid >> 6, lane = tid & 63;
  const int wr = wid >> 2, wc = wid & 3;
  const int n0 = blockIdx.x * 256, m0 = blockIdx.y * 256;
  const int NT = Kdim >> 6;
  const int rl = lane & 15, kob = (lane >> 4) << 4;
  const int brow0 = (wc & 1) * 64;

  f32x4 acc[8][4];
#pragma unroll
  for (int i = 0; i < 8; ++i)
#pragma unroll
    for (int j = 0; j < 4; ++j) acc[i][j] = (f32x4){0.f, 0.f, 0.f, 0.f};

#define STAGE_A(T, H) stage_half(A + (size_t)(m0 + (H)*128) * Kdim + (T)*64, Kdim, \
                                 sm + ((((T)&1)*4 + (H)) * 8192), tid)
#define STAGE_B(T, H) stage_half(Bt + (size_t)(n0 + (H)*128) * Kdim + (T)*64, Kdim, \
                                 sm + ((((T)&1)*4 + 2 + (H)) * 8192), tid)

  // prologue: stage tiles 0 and 1 (8 loads/thread each)
  STAGE_A(0, 0); STAGE_A(0, 1); STAGE_B(0, 0); STAGE_B(0, 1);
  STAGE_A(1, 0); STAGE_A(1, 1); STAGE_B(1, 0); STAGE_B(1, 1);
  S_VMCNT(8);                                           // tile 0 landed
  BARRIER();

  for (int t = 0; t < NT; ++t) {
    const int buf = t & 1;
    const unsigned short* Abase = sm + (buf * 4 + wr) * 8192;
    const unsigned short* Bbase = sm + (buf * 4 + 2 + (wc >> 1)) * 8192;
    bf16x8 a[4][2], b[4][2];

    // ---- P0: read A(Mq0) + B frags 0-1; MFMA quad (Mq0, N01) ----
#pragma unroll
    for (int i = 0; i < 4; ++i) {
      const int r = i * 16 + rl;
      a[i][0] = ldsf(Abase, r, kob);
      a[i][1] = ldsf(Abase, r, 64 + kob);
    }
#pragma unroll
    for (int j = 0; j < 2; ++j) {
      const int r = brow0 + j * 16 + rl;
      b[j][0] = ldsf(Bbase, r, kob);
      b[j][1] = ldsf(Bbase, r, 64 + kob);
    }
    BARRIER();
    __builtin_amdgcn_s_setprio(1);
#pragma unroll
    for (int i = 0; i < 4; ++i)
#pragma unroll
      for (int j = 0; j < 2; ++j) {
        acc[i][j] = __builtin_amdgcn_mfma_f32_16x16x32_bf16(a[i][0], b[j][0], acc[i][j], 0, 0, 0);
        acc[i][j] = __builtin_amdgcn_mfma_f32_16x16x32_bf16(a[i][1], b[j][1], acc[i][j], 0, 0, 0);
      }
    __builtin_amdgcn_s_setprio(0);
    BARRIER();

    // ---- P1: read B frags 2-3; MFMA quad (Mq0, N23) ----
#pragma unroll
    for (int j = 0; j < 2; ++j) {
      const int r = brow0 + (2 + j) * 16 + rl;
      b[2 + j][0] = ldsf(Bbase, r, kob);
      b[2 + j][1] = ldsf(Bbase, r, 64 + kob);
    }
    BARRIER();
    __builtin_amdgcn_s_setprio(1);
#pragma unroll
    for (int i = 0; i < 4; ++i)
#pragma unroll
      for (int j = 0; j < 2; ++j) {
        acc[i][2 + j] = __builtin_amdgcn_mfma_f32_16x16x32_bf16(a[i][0], b[2 + j][0], acc[i][2 + j], 0, 0, 0);
        acc[i][2 + j] = __builtin_amdgcn_mfma_f32_16x16x32_bf16(a[i][1], b[2 + j][1], acc[i][2 + j], 0, 0, 0);
      }
    __builtin_amdgcn_s_setprio(0);
    BARRIER();

    // ---- P2: read A(Mq1); stage B(t+2) (B region of this buf is dead now) ----
#pragma unroll
    for (int i = 0; i < 4; ++i) {
      const int r = 64 + i * 16 + rl;
      a[i][0] = ldsf(Abase, r, kob);
      a[i][1] = ldsf(Abase, r, 64 + kob);
    }
    if (t + 2 < NT) { STAGE_B(t + 2, 0); STAGE_B(t + 2, 1); }
    BARRIER();
    __builtin_amdgcn_s_setprio(1);
#pragma unroll
    for (int i = 0; i < 4; ++i)
#pragma unroll
      for (int j = 0; j < 2; ++j) {
        acc[4 + i][2 + j] = __builtin_amdgcn_mfma_f32_16x16x32_bf16(a[i][0], b[2 + j][0], acc[4 + i][2 + j], 0, 0, 0);
        acc[4 + i][2 + j] = __builtin_amdgcn_mfma_f32_16x16x32_bf16(a[i][1], b[2 + j][1], acc[4 + i][2 + j], 0, 0, 0);
      }
    __builtin_amdgcn_s_setprio(0);
    BARRIER();

    // ---- P3: stage A(t+2) (A region dead after P2); MFMA quad (Mq1, N01) ----
    if (t + 2 < NT) { STAGE_A(t + 2, 0); STAGE_A(t + 2, 1); }
    BARRIER();
    __builtin_amdgcn_s_setprio(1);
#pragma unroll
    for (int i = 0; i < 4; ++i)
#pragma unroll
      for (int j = 0; j < 2; ++j) {
        acc[4 + i][j] = __builtin_amdgcn_mfma_f32_16x16x32_bf16(a[i][0], b[j][0], acc[4 + i][j], 0, 0, 0);
        acc[4 + i][j] = __builtin_amdgcn_mfma_f32_16x16x32_bf16(a[i][1], b[j][1], acc[4 + i][j], 0, 0, 0);
      }
    __builtin_amdgcn_s_setprio(0);
    if (t + 2 < NT) { S_VMCNT(8); } else { S_VMCNT(0); }  // counted: tile t+1 landed, t+2 in flight
    BARRIER();
  }
#undef STAGE_A
#undef STAGE_B

  // ---- epilogue ----
  const int cr = (lane >> 4) * 4, cc = lane & 15;
#pragma unroll
  for (int mi = 0; mi < 8; ++mi) {
    const int lrow = (mi >> 2) * 64 + (mi & 3) * 16;
#pragma unroll
    for (int j = 0; j < 4; ++j) {
      const int gc = n0 + wc * 64 + j * 16 + cc;
#pragma unroll
      for (int rr = 0; rr < 4; ++rr) {
        const int gr = m0 + wr * 128 + lrow + cr + rr;
        float v = acc[mi][j][rr];
        if (MODE == 0) {
          const float bias = (gc < 1024) ? b0[gc] : ((gc < 2048) ? b1[gc - 1024] : b2[gc - 2048]);
          v += bias;
          if (gc < 2048) v = 1.f / (1.f + __expf(-v));
          ((unsigned short*)C)[(size_t)gr * Ndim + gc] = f2bf(v);
        } else {
          v += b0[gc];
          ((float*)C)[(size_t)gr * Ndim + gc] = v;
        }
      }
    }
  }
}

// ---------- flow statistics ----------
__global__ __launch_bounds__(256) void sums_k(const unsigned short* __restrict__ QKV,
                                              float* __restrict__ ksum, float* __restrict__ qsum) {
  const int bh = blockIdx.x >> 3, c = blockIdx.x & 7;
  const int b = bh >> 4, h = bh & 15;
  const int d = threadIdx.x & 63, part = threadIdx.x >> 6;
  const size_t base = (size_t)b * SEQ * 3072 + h * 64 + d;
  float qa = 0.f, ka = 0.f;
  for (int l = c * 512 + part; l < (c + 1) * 512; l += 4) {
    const size_t off = base + (size_t)l * 3072;
    qa += bf2f(QKV[off]);
    ka += bf2f(QKV[off + 1024]);
  }
  __shared__ float red[2][4][64];
  red[0][part][d] = qa; red[1][part][d] = ka;
  __syncthreads();
  if (part == 0) {
    qa = red[0][0][d] + red[0][1][d] + red[0][2][d] + red[0][3][d];
    ka = red[1][0][d] + red[1][1][d] + red[1][2][d] + red[1][3][d];
    atomicAdd(&qsum[bh * 64 + d], qa);
    atomicAdd(&ksum[bh * 64 + d], ka);
  }
}

__global__ __launch_bounds__(256) void flow1_k(const unsigned short* __restrict__ QKV,
                                               const float* __restrict__ ksum, const float* __restrict__ qsum,
                                               float* __restrict__ si, float* __restrict__ qsi,
                                               float* __restrict__ kso) {
  const int bh = blockIdx.x >> 3, c = blockIdx.x & 7;
  const int b = bh >> 4, h = bh & 15;
  const int w = threadIdx.x >> 6, lane = threadIdx.x & 63;
  const float ks = ksum[bh * 64 + lane] + FEPS;
  const float qs = qsum[bh * 64 + lane] + FEPS;
  const size_t base = (size_t)b * SEQ * 3072 + h * 64 + lane;
  float qsi_acc = 0.f, kso_acc = 0.f;
  const int l0 = c * 512 + w * 128;
  for (int l = l0; l < l0 + 128; ++l) {
    const size_t off = base + (size_t)l * 3072;
    const float qv = bf2f(QKV[off]);
    const float kv = bf2f(QKV[off + 1024]);
    float dq = (qv + FEPS) * ks;
    float dk = (kv + FEPS) * qs;
#pragma unroll
    for (int m = 1; m < 64; m <<= 1) { dq += __shfl_xor(dq, m); dk += __shfl_xor(dk, m); }
    const float siv = 1.f / dq, sov = 1.f / dk;
    if (lane == 0) si[(size_t)bh * SEQ + l] = siv;
    qsi_acc += qv * siv;
    kso_acc += kv * sov;
  }
  atomicAdd(&qsi[bh * 64 + lane], qsi_acc);
  atomicAdd(&kso[bh * 64 + lane], kso_acc);
}

__global__ __launch_bounds__(256) void flow2_k(const unsigned short* __restrict__ QKV,
                                               const float* __restrict__ qsi, const float* __restrict__ kso,
                                               float* __restrict__ sa, float* __restrict__ ee,
                                               float* __restrict__ esum) {
  const int bh = blockIdx.x >> 3, c = blockIdx.x & 7;
  const int b = bh >> 4, h = bh & 15;
  const int w = threadIdx.x >> 6, lane = threadIdx.x & 63;
  const float kov = kso[bh * 64 + lane] + FEPS;
  const float qiv = qsi[bh * 64 + lane] + FEPS;
  const size_t base = (size_t)b * SEQ * 3072 + h * 64 + lane;
  float es = 0.f;
  const int l0 = c * 512 + w * 128;
  for (int l = l0; l < l0 + 128; ++l) {
    const size_t off = base + (size_t)l * 3072;
    const float qv = bf2f(QKV[off]);
    const float kv = bf2f(QKV[off + 1024]);
    float ds = (qv + FEPS) * kov;
    float dr = (kv + FEPS) * qiv;
#pragma unroll
    for (int m = 1; m < 64; m <<= 1) { ds += __shfl_xor(ds, m); dr += __shfl_xor(dr, m); }
    const float sig = 1.f / (1.f + __expf(-ds));
    const float cs = fminf(1.f, fmaxf(-1.f, dr));
    const float e = __expf(cs);
    if (lane == 0) { sa[(size_t)bh * SEQ + l] = sig; ee[(size_t)bh * SEQ + l] = e; }
    es += e;
  }
  if (lane == 0) atomicAdd(&esum[bh], es);
}

__global__ __launch_bounds__(256) void kvpart_k(const unsigned short* __restrict__ QKV,
                                                const float* __restrict__ ee, const float* __restrict__ esum,
                                                float* __restrict__ kvp) {
  const int bh = blockIdx.x >> 3, c = blockIdx.x & 7;
  const int b = bh >> 4, h = bh & 15;
  const float Ls = 4096.f / esum[bh];
  __shared__ float kch[32][64];
  __shared__ float vch[32][64];
  const int t = threadIdx.x;
  const int sl = t >> 3, sd = (t & 7) * 8;
  const int d1 = (t >> 4) * 4, d2 = (t & 15) * 4;
  const size_t rowbase = (size_t)b * SEQ * 3072 + h * 64;
  float acc[4][4] = {};
  for (int ch = 0; ch < 16; ++ch) {
    const int l0 = c * 512 + ch * 32;
    const size_t off = rowbase + (size_t)(l0 + sl) * 3072 + sd;
    const uint4 kr = *(const uint4*)(QKV + off + 1024);
    const uint4 vr = *(const uint4*)(QKV + off + 2048);
    const float cmp = ee[(size_t)bh * SEQ + l0 + sl] * Ls;
    float kd[8], vd[8];
    decode8(kr, kd); decode8(vr, vd);
    __syncthreads();
    *(f32x4*)&kch[sl][sd]     = (f32x4){kd[0], kd[1], kd[2], kd[3]};
    *(f32x4*)&kch[sl][sd + 4] = (f32x4){kd[4], kd[5], kd[6], kd[7]};
    *(f32x4*)&vch[sl][sd]     = (f32x4){vd[0] * cmp, vd[1] * cmp, vd[2] * cmp, vd[3] * cmp};
    *(f32x4*)&vch[sl][sd + 4] = (f32x4){vd[4] * cmp, vd[5] * cmp, vd[6] * cmp, vd[7] * cmp};
    __syncthreads();
    for (int l = 0; l < 32; ++l) {
      const f32x4 ka = *(const f32x4*)&kch[l][d1];
      const f32x4 vb = *(const f32x4*)&vch[l][d2];
#pragma unroll
      for (int i = 0; i < 4; ++i)
#pragma unroll
        for (int j = 0; j < 4; ++j) acc[i][j] += ka[i] * vb[j];
    }
    __syncthreads();
  }
  float* dst = kvp + (size_t)blockIdx.x * 4096;
#pragma unroll
  for (int i = 0; i < 4; ++i)
    *(f32x4*)&dst[(d1 + i) * 64 + d2] = (f32x4){acc[i][0], acc[i][1], acc[i][2], acc[i][3]};
}

__global__ __launch_bounds__(256) void kvred_k(const float* __restrict__ kvp, float* __restrict__ kvf) {
  const int idx = blockIdx.x * 256 + threadIdx.x;
  const int bh = idx >> 12, e = idx & 4095;
  float s = 0.f;
#pragma unroll
  for (int cN = 0; cN < 8; ++cN) s += kvp[((size_t)(bh * 8 + cN) << 12) + e];
  kvf[idx] = s;
}

__global__ __launch_bounds__(256) void outk_k(const unsigned short* __restrict__ QKV,
                                              const float* __restrict__ kvf, const float* __restrict__ si,
                                              const float* __restrict__ sa,
                                              unsigned short* __restrict__ AOb) {
  const int bh = blockIdx.x >> 4, lc = blockIdx.x & 15;
  const int b = bh >> 4, h = bh & 15;
  __shared__ float kvs[4096];
  __shared__ float qs_[64 * 128];
  const int t = threadIdx.x;
  for (int i = t; i < 1024; i += 256)
    *(f32x4*)&kvs[i * 4] = *(const f32x4*)&kvf[(size_t)bh * 4096 + i * 4];
  const size_t rowbase = (size_t)b * SEQ * 3072 + h * 64;
  const int lb = (t >> 4) * 8, d2 = (t & 15) * 4;
  const int sl = t & 127, sd0 = (t >> 7) * 8;
  for (int sub = 0; sub < 2; ++sub) {
    const int l0 = lc * 256 + sub * 128;
    __syncthreads();
#pragma unroll
    for (int p = 0; p < 4; ++p) {
      const int d0 = sd0 + p * 16;
      const uint4 raw = *(const uint4*)(QKV + rowbase + (size_t)(l0 + sl) * 3072 + d0);
      float qd[8]; decode8(raw, qd);
#pragma unroll
      for (int i = 0; i < 8; ++i) qs_[(d0 + i) * 128 + sl] = qd[i];
    }
    __syncthreads();
    float acc[8][4] = {};
    for (int dd = 0; dd < 64; ++dd) {
      const f32x4 kvv = *(const f32x4*)&kvs[dd * 64 + d2];
      const f32x4 qa = *(const f32x4*)&qs_[dd * 128 + lb];
      const f32x4 qb = *(const f32x4*)&qs_[dd * 128 + lb + 4];
#pragma unroll
      for (int i = 0; i < 4; ++i)
#pragma unroll
        for (int j = 0; j < 4; ++j) { acc[i][j] += qa[i] * kvv[j]; acc[i + 4][j] += qb[i] * kvv[j]; }
    }
#pragma unroll
    for (int i = 0; i < 8; ++i) {
      const int l = l0 + lb + i;
      const size_t sidx = (size_t)bh * SEQ + l;
      const float sc = si[sidx] * sa[sidx];
      ushort4 o;
      o.x = f2bf(acc[i][0] * sc); o.y = f2bf(acc[i][1] * sc);
      o.z = f2bf(acc[i][2] * sc); o.w = f2bf(acc[i][3] * sc);
      *(ushort4*)(AOb + (size_t)(b * SEQ + l) * 1024 + h * 64 + d2) = o;
    }
  }
}

extern "C" void kernel_launch(void* const* d_in, const int* in_sizes, int n_in,
                              void* d_out, int out_size, void* d_ws, size_t ws_size,
                              hipStream_t stream) {
  const float* x  = (const float*)d_in[0];
  const float* Wq = (const float*)d_in[1];
  const float* bq = (const float*)d_in[2];
  const float* Wk = (const float*)d_in[3];
  const float* bk = (const float*)d_in[4];
  const float* Wv = (const float*)d_in[5];
  const float* bv = (const float*)d_in[6];
  const float* Wo = (const float*)d_in[7];
  const float* bo = (const float*)d_in[8];
  char* ws = (char*)d_ws;
  unsigned short* Xb    = (unsigned short*)(ws + XB_OFF);
  unsigned short* Wqkvt = (unsigned short*)(ws + WQKV_OFF);
  unsigned short* Wot   = (unsigned short*)(ws + WO_OFF);
  unsigned short* QKV   = (unsigned short*)(ws + QKV_OFF);
  unsigned short* AOb   = (unsigned short*)(ws + AOB_OFF);
  float* ksum = (float*)(ws + KSUM_OFF);
  float* qsum = (float*)(ws + QSUM_OFF);
  float* qsi  = (float*)(ws + QSI_OFF);
  float* kso  = (float*)(ws + KSO_OFF);
  float* esum = (float*)(ws + ESUM_OFF);
  float* si   = (float*)(ws + SI_OFF);
  float* sa   = (float*)(ws + SA_OFF);
  float* ee   = (float*)(ws + EE_OFF);
  float* kvf  = (float*)(ws + KVF_OFF);
  float* kvp  = (float*)(ws + KVP_OFF);

  (void)hipMemsetAsync(ws + ST_OFF, 0, 81920, stream);  // zero atomic accumulators
  conv_x_k<<<2048, 256, 0, stream>>>(x, Xb, MTOK * DMODEL);
  convw_k<<<dim3(16, 16, 4), 256, 0, stream>>>(Wq, Wk, Wv, Wo, Wqkvt, Wot);
  gemm8p<0><<<dim3(12, 64), 512, 0, stream>>>(Xb, Wqkvt, bq, bk, bv, (void*)QKV, 3072, 1024);
  sums_k<<<NBH * 8, 256, 0, stream>>>(QKV, ksum, qsum);
  flow1_k<<<NBH * 8, 256, 0, stream>>>(QKV, ksum, qsum, si, qsi, kso);
  flow2_k<<<NBH * 8, 256, 0, stream>>>(QKV, qsi, kso, sa, ee, esum);
  kvpart_k<<<NBH * 8, 256, 0, stream>>>(QKV, ee, esum, kvp);
  kvred_k<<<1024, 256, 0, stream>>>(kvp, kvf);
  outk_k<<<NBH * 16, 256, 0, stream>>>(QKV, kvf, si, sa, AOb);
  gemm8p<1><<<dim3(4, 64), 512, 0, stream>>>(AOb, Wot, bo, nullptr, nullptr, d_out, 1024, 1024);
}